// Round 1
// baseline (604.078 us; speedup 1.0000x reference)
//
#include <hip/hip_runtime.h>
#include <cmath>

#define THETA 0.5f
#define EPS 1e-5f

// ---------------- global LN stats: sum & sumsq over all of x ----------------
__global__ __launch_bounds__(256) void stats_kernel(const float* __restrict__ x,
                                                    float* __restrict__ stats, int n4) {
  int tid = blockIdx.x * blockDim.x + threadIdx.x;
  int stride = gridDim.x * blockDim.x;
  float s = 0.f, ss = 0.f;
  const float4* x4 = (const float4*)x;
  for (int i = tid; i < n4; i += stride) {
    float4 v = x4[i];
    s  += v.x + v.y + v.z + v.w;
    ss += v.x * v.x + v.y * v.y + v.z * v.z + v.w * v.w;
  }
  for (int off = 32; off; off >>= 1) {
    s  += __shfl_down(s, off);
    ss += __shfl_down(ss, off);
  }
  __shared__ float ls[4], lss[4];
  int lane = threadIdx.x & 63, wid = threadIdx.x >> 6;
  if (lane == 0) { ls[wid] = s; lss[wid] = ss; }
  __syncthreads();
  if (threadIdx.x == 0) {
    float a = 0.f, b = 0.f;
    for (int w = 0; w < 4; ++w) { a += ls[w]; b += lss[w]; }
    atomicAdd(&stats[0], a);
    atomicAdd(&stats[1], b);
  }
}

// ---------------- PDC conv (k and v fused; share the x tile) ----------------
// out[b,co,oh,ow] = sum_ci sum_{p!=4} w8[p'] * x[b,ci,2oh-1+ky,2ow-1+kx]
//                 - THETA * (sum_t w8[t]) * x[b,ci,2oh,2ow]
__global__ __launch_bounds__(256) void pdc_conv_kernel(
    const float* __restrict__ x,   // (8,64,64,64)
    const float* __restrict__ wk,  // (64,64,8)
    const float* __restrict__ wv,  // (64,64,8)
    float* __restrict__ Kc,        // (8,64,1024)
    float* __restrict__ Vc) {
  int oh = blockIdx.x;   // 0..31
  int bb = blockIdx.y;   // 0..7
  __shared__ float xs[64][3][64];  // 48KB: 3 input rows, all ci
  const float* xb = x + (size_t)bb * 64 * 64 * 64;
  int r1 = 2 * oh;  // center input row
  for (int i = 0; i < 48; ++i) {
    int idx = threadIdx.x + i * 256;   // 0..12287
    int ci = idx / 192;
    int rem = idx - ci * 192;
    int r = rem >> 6;        // 0..2
    int col = rem & 63;
    int row = r1 - 1 + r;    // max 63, min -1 (oh==0)
    float v = 0.f;
    if (row >= 0) v = xb[((size_t)ci * 64 + row) * 64 + col];
    xs[ci][r][col] = v;
  }
  __syncthreads();
  int co  = threadIdx.x >> 2;  // 0..63
  int owl = threadIdx.x & 3;   // 0..3 -> ow = owl + 4*i
  float accK[8], accV[8];
#pragma unroll
  for (int i = 0; i < 8; ++i) { accK[i] = 0.f; accV[i] = 0.f; }
  const float* wkc = wk + (size_t)co * 512;
  const float* wvc = wv + (size_t)co * 512;
  for (int ci = 0; ci < 64; ++ci) {
    float4 k0 = *(const float4*)(wkc + ci * 8);
    float4 k1 = *(const float4*)(wkc + ci * 8 + 4);
    float4 v0 = *(const float4*)(wvc + ci * 8);
    float4 v1 = *(const float4*)(wvc + ci * 8 + 4);
    float kdk = k0.x + k0.y + k0.z + k0.w + k1.x + k1.y + k1.z + k1.w;
    float kdv = v0.x + v0.y + v0.z + v0.w + v1.x + v1.y + v1.z + v1.w;
    float wK[9] = {k0.x, k0.y, k0.z, k0.w, -THETA * kdk, k1.x, k1.y, k1.z, k1.w};
    float wV[9] = {v0.x, v0.y, v0.z, v0.w, -THETA * kdv, v1.x, v1.y, v1.z, v1.w};
#pragma unroll
    for (int p = 0; p < 9; ++p) {
      int ky = p / 3, kx = p - ky * 3;
#pragma unroll
      for (int i = 0; i < 8; ++i) {
        int ow = owl + 4 * i;
        int col = 2 * ow - 1 + kx;
        float xv = (col >= 0 && col < 64) ? xs[ci][ky][col] : 0.f;
        accK[i] = fmaf(wK[p], xv, accK[i]);
        accV[i] = fmaf(wV[p], xv, accV[i]);
      }
    }
  }
#pragma unroll
  for (int i = 0; i < 8; ++i) {
    int ow = owl + 4 * i;
    size_t o = ((size_t)bb * 64 + co) * 1024 + (size_t)oh * 32 + ow;
    Kc[o] = accK[i];
    Vc[o] = accV[i];
  }
}

// ---------------- projection: out[b,r,d] = sum_c A[b,c,r]*W[d,c] + bias[d] --
// optional global-LN on A. Wave w handles 8 consecutive d (scalar W loads).
__global__ __launch_bounds__(256) void proj_kernel(
    const float* __restrict__ A,     // (B, 64, R) channel-major
    const float* __restrict__ W,     // (128, 64)
    const float* __restrict__ bias,  // (128)
    float* __restrict__ out,         // (B, R, 128)
    const float* __restrict__ stats, int R, int doLN, int Ntot) {
  int r0 = blockIdx.x * 64;
  int d0 = blockIdx.y * 32;
  int bb = blockIdx.z;
  float m = 0.f, rs = 1.f;
  if (doLN) {
    float inv = 1.0f / (float)Ntot;
    m = stats[0] * inv;
    float v = stats[1] * inv - m * m;
    rs = rsqrtf(v + EPS);
  }
  __shared__ float As[64][64];
  const float* Ab = A + (size_t)bb * 64 * R;
  for (int i = 0; i < 16; ++i) {
    int idx = threadIdx.x + i * 256;
    int c = idx >> 6, rr = idx & 63;
    float v = Ab[(size_t)c * R + r0 + rr];
    if (doLN) v = (v - m) * rs;
    As[c][rr] = v;
  }
  __syncthreads();
  int lane = threadIdx.x & 63;
  int w = __builtin_amdgcn_readfirstlane(threadIdx.x >> 6);
  int dbase = d0 + w * 8;
  float acc[8];
#pragma unroll
  for (int i = 0; i < 8; ++i) acc[i] = bias[dbase + i];
  for (int c = 0; c < 64; ++c) {
    float a = As[c][lane];
#pragma unroll
    for (int i = 0; i < 8; ++i)
      acc[i] = fmaf(a, W[(size_t)(dbase + i) * 64 + c], acc[i]);
  }
  float* op = out + ((size_t)bb * R + r0 + lane) * 128 + dbase;
  *(float4*)op       = make_float4(acc[0], acc[1], acc[2], acc[3]);
  *(float4*)(op + 4) = make_float4(acc[4], acc[5], acc[6], acc[7]);
}

// ---------------- flash attention, thread-per-query-row ----------------
#define CHUNK 128
__global__ __launch_bounds__(256) void attn_kernel(
    const float* __restrict__ Q,   // (8,4096,128)
    const float* __restrict__ K,   // (8,1024,128)
    const float* __restrict__ V,   // (8,1024,128)
    const float* __restrict__ Bb,  // (4,4096,1024)
    float* __restrict__ O) {       // (8,4096,128)
  int jt = blockIdx.x;  // 0..15
  int h  = blockIdx.y;  // 0..3
  int bb = blockIdx.z;  // 0..7
  int j = jt * 256 + threadIdx.x;
  __shared__ float Ks[CHUNK][32];
  __shared__ float Vs[CHUNK][32];
  float q[32];
  const float* qp = Q + ((size_t)bb * 4096 + j) * 128 + h * 32;
#pragma unroll
  for (int i = 0; i < 8; ++i) {
    float4 t = *(const float4*)(qp + i * 4);
    q[4 * i] = t.x; q[4 * i + 1] = t.y; q[4 * i + 2] = t.z; q[4 * i + 3] = t.w;
  }
  const float scale = 0.17677669529663687f;  // 1/sqrt(32)
  float mrun = -1e30f, l = 0.f;
  float acc[32];
#pragma unroll
  for (int i = 0; i < 32; ++i) acc[i] = 0.f;
  const float4* Bp4 = (const float4*)(Bb + ((size_t)h * 4096 + j) * 1024);
  for (int kc = 0; kc < 1024; kc += CHUNK) {
    __syncthreads();
    for (int i = 0; i < 4; ++i) {
      int idx = threadIdx.x + i * 256;       // 0..1023 float4s
      int kk = idx >> 3, dd = (idx & 7) * 4;
      size_t g = ((size_t)bb * 1024 + kc + kk) * 128 + h * 32 + dd;
      *(float4*)&Ks[kk][dd] = *(const float4*)&K[g];
      *(float4*)&Vs[kk][dd] = *(const float4*)&V[g];
    }
    __syncthreads();
    for (int kk = 0; kk < CHUNK; kk += 4) {
      float4 b4 = Bp4[(kc + kk) >> 2];
      float bs[4] = {b4.x, b4.y, b4.z, b4.w};
#pragma unroll
      for (int u = 0; u < 4; ++u) {
        int kki = kk + u;
        float s = 0.f;
#pragma unroll
        for (int dd = 0; dd < 32; ++dd) s = fmaf(q[dd], Ks[kki][dd], s);
        s = fmaf(s, scale, bs[u]);
        if (s > mrun) {                       // rare after warm-up
          float corr = __expf(mrun - s);
          mrun = s;
          l *= corr;
#pragma unroll
          for (int dd = 0; dd < 32; ++dd) acc[dd] *= corr;
        }
        float p = __expf(s - mrun);
        l += p;
#pragma unroll
        for (int dd = 0; dd < 32; ++dd) acc[dd] = fmaf(p, Vs[kki][dd], acc[dd]);
      }
    }
  }
  float inv = 1.0f / l;
  float* op = O + ((size_t)bb * 4096 + j) * 128 + h * 32;
#pragma unroll
  for (int i = 0; i < 8; ++i) {
    *(float4*)(op + i * 4) = make_float4(acc[4 * i] * inv, acc[4 * i + 1] * inv,
                                         acc[4 * i + 2] * inv, acc[4 * i + 3] * inv);
  }
}

// ---------------- output projection + residual (flat reindex) ----------------
__global__ __launch_bounds__(256) void outproj_kernel(
    const float* __restrict__ O,    // (8,4096,128)
    const float* __restrict__ Wo,   // (64,128)
    const float* __restrict__ bo,   // (64)
    const float* __restrict__ x,    // (8,262144) flat
    float* __restrict__ out) {
  int r0 = blockIdx.x * 64;
  int bb = blockIdx.y;
  __shared__ float Os[128][65];     // transposed + padded
  const float* Ob = O + ((size_t)bb * 4096 + r0) * 128;
  for (int i = 0; i < 32; ++i) {
    int idx = threadIdx.x + i * 256;  // 0..8191
    int e = idx & 127, rr = idx >> 7;
    Os[e][rr] = Ob[(size_t)rr * 128 + e];
  }
  __syncthreads();
  int lane = threadIdx.x & 63;
  int w = __builtin_amdgcn_readfirstlane(threadIdx.x >> 6);
  float acc[16];
#pragma unroll
  for (int i = 0; i < 16; ++i) acc[i] = bo[w * 16 + i];
  for (int e = 0; e < 128; ++e) {
    float a = Os[e][lane];
#pragma unroll
    for (int i = 0; i < 16; ++i)
      acc[i] = fmaf(a, Wo[(size_t)(w * 16 + i) * 128 + e], acc[i]);
  }
  size_t base = (size_t)bb * 262144 + (size_t)(r0 + lane) * 64 + w * 16;
  const float* xp = x + base;
  float* op = out + base;
#pragma unroll
  for (int i = 0; i < 16; ++i) op[i] = acc[i] + xp[i];
}

extern "C" void kernel_launch(void* const* d_in, const int* in_sizes, int n_in,
                              void* d_out, int out_size, void* d_ws, size_t ws_size,
                              hipStream_t stream) {
  const float* x    = (const float*)d_in[0];
  const float* wk   = (const float*)d_in[1];
  const float* wv   = (const float*)d_in[2];
  const float* fcqw = (const float*)d_in[3];
  const float* fcqb = (const float*)d_in[4];
  const float* fckw = (const float*)d_in[5];
  const float* fckb = (const float*)d_in[6];
  const float* fcvw = (const float*)d_in[7];
  const float* fcvb = (const float*)d_in[8];
  const float* fcow = (const float*)d_in[9];
  const float* fcob = (const float*)d_in[10];
  const float* Bb   = (const float*)d_in[11];
  float* out = (float*)d_out;
  float* ws  = (float*)d_ws;

  float* stats = ws;                 // 2 floats (zeroed below)
  float* Q  = ws + 16;               // 8*4096*128 = 4194304
  float* Kk = Q  + 4194304;          // 8*1024*128 = 1048576
  float* Vv = Kk + 1048576;          // 1048576
  float* Kc = Vv + 1048576;          // 8*64*1024 = 524288
  float* Vc = Kc + 524288;           // 524288
  float* O  = Vc + 524288;           // 4194304   (total ~46.1 MB)

  hipMemsetAsync(stats, 0, 2 * sizeof(float), stream);
  stats_kernel<<<dim3(512), dim3(256), 0, stream>>>(x, stats, 2097152 / 4);
  pdc_conv_kernel<<<dim3(32, 8), dim3(256), 0, stream>>>(x, wk, wv, Kc, Vc);
  proj_kernel<<<dim3(64, 4, 8), dim3(256), 0, stream>>>(x,  fcqw, fcqb, Q,  stats, 4096, 1, 2097152);
  proj_kernel<<<dim3(16, 4, 8), dim3(256), 0, stream>>>(Kc, fckw, fckb, Kk, stats, 1024, 0, 1);
  proj_kernel<<<dim3(16, 4, 8), dim3(256), 0, stream>>>(Vc, fcvw, fcvb, Vv, stats, 1024, 0, 1);
  attn_kernel<<<dim3(16, 4, 8), dim3(256), 0, stream>>>(Q, Kk, Vv, Bb, O);
  outproj_kernel<<<dim3(64, 8), dim3(256), 0, stream>>>(O, fcow, fcob, x, out);
}

// Round 2
// 312.153 us; speedup vs baseline: 1.9352x; 1.9352x over previous
//
#include <hip/hip_runtime.h>
#include <cmath>

#define THETA 0.5f
#define EPS 1e-5f

typedef __attribute__((ext_vector_type(8))) short bf16x8;
typedef __attribute__((ext_vector_type(4))) float f32x4;

__device__ inline unsigned short f2b(float f) {
  unsigned u = __builtin_bit_cast(unsigned, f);
  return (unsigned short)((u + 0x7fffu + ((u >> 16) & 1u)) >> 16);
}

// ---------------- global LN stats: sum & sumsq over all of x ----------------
__global__ __launch_bounds__(256) void stats_kernel(const float* __restrict__ x,
                                                    float* __restrict__ stats, int n4) {
  int tid = blockIdx.x * blockDim.x + threadIdx.x;
  int stride = gridDim.x * blockDim.x;
  float s = 0.f, ss = 0.f;
  const float4* x4 = (const float4*)x;
  for (int i = tid; i < n4; i += stride) {
    float4 v = x4[i];
    s  += v.x + v.y + v.z + v.w;
    ss += v.x * v.x + v.y * v.y + v.z * v.z + v.w * v.w;
  }
  for (int off = 32; off; off >>= 1) {
    s  += __shfl_down(s, off);
    ss += __shfl_down(ss, off);
  }
  __shared__ float ls[4], lss[4];
  int lane = threadIdx.x & 63, wid = threadIdx.x >> 6;
  if (lane == 0) { ls[wid] = s; lss[wid] = ss; }
  __syncthreads();
  if (threadIdx.x == 0) {
    float a = 0.f, b = 0.f;
    for (int w = 0; w < 4; ++w) { a += ls[w]; b += lss[w]; }
    atomicAdd(&stats[0], a);
    atomicAdd(&stats[1], b);
  }
}

// ---------------- PDC conv (k and v fused; share the x tile) ----------------
__global__ __launch_bounds__(256) void pdc_conv_kernel(
    const float* __restrict__ x,   // (8,64,64,64)
    const float* __restrict__ wk,  // (64,64,8)
    const float* __restrict__ wv,  // (64,64,8)
    float* __restrict__ Kc,        // (8,64,1024)
    float* __restrict__ Vc) {
  int oh = blockIdx.x;   // 0..31
  int bb = blockIdx.y;   // 0..7
  __shared__ float xs[64][3][64];
  const float* xb = x + (size_t)bb * 64 * 64 * 64;
  int r1 = 2 * oh;
  for (int i = 0; i < 48; ++i) {
    int idx = threadIdx.x + i * 256;
    int ci = idx / 192;
    int rem = idx - ci * 192;
    int r = rem >> 6;
    int col = rem & 63;
    int row = r1 - 1 + r;
    float v = 0.f;
    if (row >= 0) v = xb[((size_t)ci * 64 + row) * 64 + col];
    xs[ci][r][col] = v;
  }
  __syncthreads();
  int co  = threadIdx.x >> 2;
  int owl = threadIdx.x & 3;
  float accK[8], accV[8];
#pragma unroll
  for (int i = 0; i < 8; ++i) { accK[i] = 0.f; accV[i] = 0.f; }
  const float* wkc = wk + (size_t)co * 512;
  const float* wvc = wv + (size_t)co * 512;
  for (int ci = 0; ci < 64; ++ci) {
    float4 k0 = *(const float4*)(wkc + ci * 8);
    float4 k1 = *(const float4*)(wkc + ci * 8 + 4);
    float4 v0 = *(const float4*)(wvc + ci * 8);
    float4 v1 = *(const float4*)(wvc + ci * 8 + 4);
    float kdk = k0.x + k0.y + k0.z + k0.w + k1.x + k1.y + k1.z + k1.w;
    float kdv = v0.x + v0.y + v0.z + v0.w + v1.x + v1.y + v1.z + v1.w;
    float wK[9] = {k0.x, k0.y, k0.z, k0.w, -THETA * kdk, k1.x, k1.y, k1.z, k1.w};
    float wV[9] = {v0.x, v0.y, v0.z, v0.w, -THETA * kdv, v1.x, v1.y, v1.z, v1.w};
#pragma unroll
    for (int p = 0; p < 9; ++p) {
      int ky = p / 3, kx = p - ky * 3;
#pragma unroll
      for (int i = 0; i < 8; ++i) {
        int ow = owl + 4 * i;
        int col = 2 * ow - 1 + kx;
        float xv = (col >= 0 && col < 64) ? xs[ci][ky][col] : 0.f;
        accK[i] = fmaf(wK[p], xv, accK[i]);
        accV[i] = fmaf(wV[p], xv, accV[i]);
      }
    }
  }
#pragma unroll
  for (int i = 0; i < 8; ++i) {
    int ow = owl + 4 * i;
    size_t o = ((size_t)bb * 64 + co) * 1024 + (size_t)oh * 32 + ow;
    Kc[o] = accK[i];
    Vc[o] = accV[i];
  }
}

// ------- projection -> bf16, head-separated layouts for MFMA attention -----
// A (B,64,R) channel-major; W (128,64); out:
//   transp=0: (B, 4, R, 32) bf16 row-major (Q, K)
//   transp=1: (B, 4, 32, R) bf16 d-major   (V transposed)
__global__ __launch_bounds__(256) void proj_kernel(
    const float* __restrict__ A, const float* __restrict__ W,
    const float* __restrict__ bias, unsigned short* __restrict__ out,
    const float* __restrict__ stats, int R, int doLN, int Ntot, int transp) {
  int r0 = blockIdx.x * 64;
  int h  = blockIdx.y;           // head, d0 = h*32
  int bb = blockIdx.z;
  float m = 0.f, rs = 1.f;
  if (doLN) {
    float inv = 1.0f / (float)Ntot;
    m = stats[0] * inv;
    float v = stats[1] * inv - m * m;
    rs = rsqrtf(v + EPS);
  }
  __shared__ float As[64][64];
  const float* Ab = A + (size_t)bb * 64 * R;
  for (int i = 0; i < 16; ++i) {
    int idx = threadIdx.x + i * 256;
    int c = idx >> 6, rr = idx & 63;
    float v = Ab[(size_t)c * R + r0 + rr];
    if (doLN) v = (v - m) * rs;
    As[c][rr] = v;
  }
  __syncthreads();
  int lane = threadIdx.x & 63;
  int w = __builtin_amdgcn_readfirstlane(threadIdx.x >> 6);
  int dbase = h * 32 + w * 8;    // global output dim
  float acc[8];
#pragma unroll
  for (int i = 0; i < 8; ++i) acc[i] = bias[dbase + i];
  for (int c = 0; c < 64; ++c) {
    float a = As[c][lane];
#pragma unroll
    for (int i = 0; i < 8; ++i)
      acc[i] = fmaf(a, W[(size_t)(dbase + i) * 64 + c], acc[i]);
  }
  size_t bh = (size_t)bb * 4 + h;
  if (!transp) {
    unsigned p0 = f2b(acc[0]) | ((unsigned)f2b(acc[1]) << 16);
    unsigned p1 = f2b(acc[2]) | ((unsigned)f2b(acc[3]) << 16);
    unsigned p2 = f2b(acc[4]) | ((unsigned)f2b(acc[5]) << 16);
    unsigned p3 = f2b(acc[6]) | ((unsigned)f2b(acc[7]) << 16);
    *(uint4*)(out + (bh * R + r0 + lane) * 32 + w * 8) = make_uint4(p0, p1, p2, p3);
  } else {
#pragma unroll
    for (int i = 0; i < 8; ++i)
      out[(bh * 32 + w * 8 + i) * (size_t)R + r0 + lane] = f2b(acc[i]);
  }
}

// ---------------- MFMA flash attention ----------------
// Block: 256 thr (4 waves), wave w owns 16 queries. Grid (qt*8+b, h).
__global__ __launch_bounds__(256) void attn_mfma_kernel(
    const unsigned short* __restrict__ Qb,  // (8,4,4096,32) bf16
    const unsigned short* __restrict__ Kb,  // (8,4,1024,32) bf16
    const unsigned short* __restrict__ Vtb, // (8,4,32,1024) bf16
    const float* __restrict__ Bb,           // (4,4096,1024) f32
    float* __restrict__ O) {                // (8,4096,128) f32
  int b  = blockIdx.x & 7;
  int qt = blockIdx.x >> 3;     // 0..63
  int h  = blockIdx.y;
  int tid = threadIdx.x;
  int w = tid >> 6, lane = tid & 63;
  int g = lane >> 4, li = lane & 15;

  __shared__ unsigned short Ks[128][40];      // pad 8 -> 2-way max
  __shared__ unsigned short Vs[32][136];      // pad 8
  __shared__ unsigned short Ps[4][16][136];   // per-wave P tile

  size_t bh = (size_t)b * 4 + h;
  int q0 = qt * 64 + w * 16;
  bf16x8 qf = *(const bf16x8*)(Qb + (bh * 4096 + q0 + li) * 32 + g * 8);

  const float* Bp = Bb + ((size_t)h * 4096 + q0) * 1024;
  const unsigned short* Kg = Kb + bh * 1024 * 32;
  const unsigned short* Vg = Vtb + bh * 32 * 1024;

  float m_run[4] = {-1e30f, -1e30f, -1e30f, -1e30f};
  float l_run[4] = {0.f, 0.f, 0.f, 0.f};
  f32x4 acc0 = {0.f, 0.f, 0.f, 0.f}, acc1 = {0.f, 0.f, 0.f, 0.f};
  const float scale = 0.17677669529663687f;

  for (int jc = 0; jc < 1024; jc += 128) {
    __syncthreads();
    {   // stage K chunk (128 x 32)
      int row = tid >> 1, half = tid & 1;
      const uint4* src = (const uint4*)(Kg + (size_t)(jc + row) * 32 + half * 16);
      uint4 a = src[0], c = src[1];
      *(uint4*)&Ks[row][half * 16] = a;
      *(uint4*)&Ks[row][half * 16 + 8] = c;
      // stage Vt chunk (32 x 128)
      int vr = tid >> 3, vseg = tid & 7;
      const uint4* vsrc = (const uint4*)(Vg + (size_t)vr * 1024 + jc + vseg * 16);
      uint4 v0 = vsrc[0], v1 = vsrc[1];
      *(uint4*)&Vs[vr][vseg * 16] = v0;
      *(uint4*)&Vs[vr][vseg * 16 + 8] = v1;
    }
    __syncthreads();

    // S tiles: 8 x (16q x 16j), K(dim)=32 in one MFMA each
    float S[8][4];
#pragma unroll
    for (int t = 0; t < 8; ++t) {
      bf16x8 kf = *(const bf16x8*)&Ks[t * 16 + li][g * 8];
      f32x4 s = __builtin_amdgcn_mfma_f32_16x16x32_bf16(qf, kf, (f32x4){0.f, 0.f, 0.f, 0.f}, 0, 0, 0);
      int col = jc + t * 16 + li;
#pragma unroll
      for (int r = 0; r < 4; ++r) {
        float bias = Bp[(size_t)(g * 4 + r) * 1024 + col];
        S[t][r] = fmaf(s[r], scale, bias);
      }
    }

    // row max (rows live in regs; cols across the 16-lane group)
    float rmax[4];
#pragma unroll
    for (int r = 0; r < 4; ++r) {
      float mx = S[0][r];
#pragma unroll
      for (int t = 1; t < 8; ++t) mx = fmaxf(mx, S[t][r]);
      mx = fmaxf(mx, __shfl_xor(mx, 1));
      mx = fmaxf(mx, __shfl_xor(mx, 2));
      mx = fmaxf(mx, __shfl_xor(mx, 4));
      mx = fmaxf(mx, __shfl_xor(mx, 8));
      rmax[r] = mx;
    }

    float corr[4];
#pragma unroll
    for (int r = 0; r < 4; ++r) {
      float mn = fmaxf(m_run[r], rmax[r]);
      corr[r] = __expf(m_run[r] - mn);
      m_run[r] = mn;
    }

    float rsum[4] = {0.f, 0.f, 0.f, 0.f};
#pragma unroll
    for (int t = 0; t < 8; ++t) {
#pragma unroll
      for (int r = 0; r < 4; ++r) {
        float p = __expf(S[t][r] - m_run[r]);
        rsum[r] += p;
        Ps[w][g * 4 + r][t * 16 + li] = f2b(p);
      }
    }
#pragma unroll
    for (int r = 0; r < 4; ++r) {
      float sm = rsum[r];
      sm += __shfl_xor(sm, 1);
      sm += __shfl_xor(sm, 2);
      sm += __shfl_xor(sm, 4);
      sm += __shfl_xor(sm, 8);
      l_run[r] = l_run[r] * corr[r] + sm;
      acc0[r] *= corr[r];
      acc1[r] *= corr[r];
    }

    // PV: O(16x32) += P(16x128) * V(128x32)
#pragma unroll
    for (int js = 0; js < 4; ++js) {
      bf16x8 pf  = *(const bf16x8*)&Ps[w][li][js * 32 + g * 8];
      bf16x8 vf0 = *(const bf16x8*)&Vs[li][js * 32 + g * 8];
      bf16x8 vf1 = *(const bf16x8*)&Vs[16 + li][js * 32 + g * 8];
      acc0 = __builtin_amdgcn_mfma_f32_16x16x32_bf16(pf, vf0, acc0, 0, 0, 0);
      acc1 = __builtin_amdgcn_mfma_f32_16x16x32_bf16(pf, vf1, acc1, 0, 0, 0);
    }
  }

#pragma unroll
  for (int r = 0; r < 4; ++r) {
    float inv = 1.0f / l_run[r];
    size_t row = (size_t)b * 4096 + q0 + g * 4 + r;
    O[row * 128 + h * 32 + li]      = acc0[r] * inv;
    O[row * 128 + h * 32 + 16 + li] = acc1[r] * inv;
  }
}

// ---------------- output projection + residual (flat reindex) ----------------
__global__ __launch_bounds__(256) void outproj_kernel(
    const float* __restrict__ O,    // (8,4096,128)
    const float* __restrict__ Wo,   // (64,128)
    const float* __restrict__ bo,   // (64)
    const float* __restrict__ x,    // (8,262144) flat
    float* __restrict__ out) {
  int r0 = blockIdx.x * 64;
  int bb = blockIdx.y;
  __shared__ float Os[128][65];
  const float* Ob = O + ((size_t)bb * 4096 + r0) * 128;
  for (int i = 0; i < 32; ++i) {
    int idx = threadIdx.x + i * 256;
    int e = idx & 127, rr = idx >> 7;
    Os[e][rr] = Ob[(size_t)rr * 128 + e];
  }
  __syncthreads();
  int lane = threadIdx.x & 63;
  int w = __builtin_amdgcn_readfirstlane(threadIdx.x >> 6);
  float acc[16];
#pragma unroll
  for (int i = 0; i < 16; ++i) acc[i] = bo[w * 16 + i];
  for (int e = 0; e < 128; ++e) {
    float a = Os[e][lane];
#pragma unroll
    for (int i = 0; i < 16; ++i)
      acc[i] = fmaf(a, Wo[(size_t)(w * 16 + i) * 128 + e], acc[i]);
  }
  size_t base = (size_t)bb * 262144 + (size_t)(r0 + lane) * 64 + w * 16;
  const float* xp = x + base;
  float* op = out + base;
#pragma unroll
  for (int i = 0; i < 16; ++i) op[i] = acc[i] + xp[i];
}

extern "C" void kernel_launch(void* const* d_in, const int* in_sizes, int n_in,
                              void* d_out, int out_size, void* d_ws, size_t ws_size,
                              hipStream_t stream) {
  const float* x    = (const float*)d_in[0];
  const float* wk   = (const float*)d_in[1];
  const float* wv   = (const float*)d_in[2];
  const float* fcqw = (const float*)d_in[3];
  const float* fcqb = (const float*)d_in[4];
  const float* fckw = (const float*)d_in[5];
  const float* fckb = (const float*)d_in[6];
  const float* fcvw = (const float*)d_in[7];
  const float* fcvb = (const float*)d_in[8];
  const float* fcow = (const float*)d_in[9];
  const float* fcob = (const float*)d_in[10];
  const float* Bb   = (const float*)d_in[11];
  float* out = (float*)d_out;
  float* ws  = (float*)d_ws;

  float* stats = ws;                          // 16 floats
  float* Kc = ws + 16;                        // 8*64*1024
  float* Vc = Kc + 524288;
  float* O  = Vc + 524288;                    // 8*4096*128
  unsigned short* Qb  = (unsigned short*)(O + 4194304);  // 8*4*4096*32 bf16
  unsigned short* Kb  = Qb + 4194304;         // 8*4*1024*32 bf16
  unsigned short* Vtb = Kb + 1048576;         // 8*4*32*1024 bf16

  hipMemsetAsync(stats, 0, 2 * sizeof(float), stream);
  stats_kernel<<<dim3(512), dim3(256), 0, stream>>>(x, stats, 2097152 / 4);
  pdc_conv_kernel<<<dim3(32, 8), dim3(256), 0, stream>>>(x, wk, wv, Kc, Vc);
  proj_kernel<<<dim3(64, 4, 8), dim3(256), 0, stream>>>(x,  fcqw, fcqb, Qb,  stats, 4096, 1, 2097152, 0);
  proj_kernel<<<dim3(16, 4, 8), dim3(256), 0, stream>>>(Kc, fckw, fckb, Kb,  stats, 1024, 0, 1, 0);
  proj_kernel<<<dim3(16, 4, 8), dim3(256), 0, stream>>>(Vc, fcvw, fcvb, Vtb, stats, 1024, 0, 1, 1);
  attn_mfma_kernel<<<dim3(512, 4), dim3(256), 0, stream>>>(Qb, Kb, Vtb, Bb, O);
  outproj_kernel<<<dim3(64, 8), dim3(256), 0, stream>>>(O, fcow, fcob, x, out);
}